// Round 3
// baseline (497.729 us; speedup 1.0000x reference)
//
#include <hip/hip_runtime.h>

#define B_ 64
#define L_ 4096
#define N_ 128
#define F_ 2049
#define M_ 2048   // packed complex FFT size (L/2)

// padded LDS index: +1 float2 per 8 -> stage-0 scatter lands uniform mod 16
__device__ __forceinline__ int pidx(int a) { return a + (a >> 3); }

__device__ __forceinline__ float2 cadd(float2 a, float2 b) { return make_float2(a.x + b.x, a.y + b.y); }
__device__ __forceinline__ float2 csub(float2 a, float2 b) { return make_float2(a.x - b.x, a.y - b.y); }
__device__ __forceinline__ float2 cmul(float2 a, float2 b) {
  return make_float2(a.x * b.x - a.y * b.y, a.x * b.y + a.y * b.x);
}
template <int SGN>
__device__ __forceinline__ float2 mulsi(float2 a) {  // * (SGN * i)
  return (SGN > 0) ? make_float2(-a.y, a.x) : make_float2(a.y, -a.x);
}

template <int SGN>
__device__ __forceinline__ void dft8(float2* v) {
  const float C = 0.70710678118654752f;
  float2 t0 = cadd(v[0], v[4]), t1 = csub(v[0], v[4]);
  float2 t2 = cadd(v[2], v[6]), t3 = mulsi<SGN>(csub(v[2], v[6]));
  float2 t4 = cadd(v[1], v[5]), t5 = csub(v[1], v[5]);
  float2 t6 = cadd(v[3], v[7]), t7 = mulsi<SGN>(csub(v[3], v[7]));
  float2 u0 = cadd(t0, t2), u1 = csub(t0, t2);
  float2 u2 = cadd(t1, t3), u3 = csub(t1, t3);
  float2 u4 = cadd(t4, t6), u5 = csub(t4, t6);
  float2 u6 = cadd(t5, t7), u7 = csub(t5, t7);
  float2 w1 = make_float2(C, (SGN > 0) ? C : -C);    // e^{s i pi/4}
  float2 w3 = make_float2(-C, (SGN > 0) ? C : -C);   // e^{s i 3pi/4}
  float2 a5 = mulsi<SGN>(u5);
  float2 b6 = cmul(u6, w1);
  float2 b7 = cmul(u7, w3);
  v[0] = cadd(u0, u4); v[4] = csub(u0, u4);
  v[2] = cadd(u1, a5); v[6] = csub(u1, a5);
  v[1] = cadd(u2, b6); v[5] = csub(u2, b6);
  v[3] = cadd(u3, b7); v[7] = csub(u3, b7);
}

template <int SGN>
__device__ __forceinline__ void dft4(float2* v) {
  float2 e0 = cadd(v[0], v[2]), e1 = csub(v[0], v[2]);
  float2 o0 = cadd(v[1], v[3]), o1 = mulsi<SGN>(csub(v[1], v[3]));
  v[0] = cadd(e0, o0); v[2] = csub(e0, o0);
  v[1] = cadd(e1, o1); v[3] = csub(e1, o1);
}

// post-DFT Stockham twiddle: v[k] *= exp(SGN * 2pi i * k * pm / 2048)
template <int SGN>
__device__ __forceinline__ void tw8(float2* v, int pm) {
  float ang = (float)pm * 0.00306796157577128245f;  // 2pi/2048
  float sv, cv;
  __sincosf(ang, &sv, &cv);
  float2 w = make_float2(cv, (SGN > 0) ? sv : -sv);
  float2 wk = w;
  v[1] = cmul(v[1], wk);
#pragma unroll
  for (int k = 2; k < 8; ++k) { wk = cmul(wk, w); v[k] = cmul(v[k], wk); }
}

// 2048-pt complex Stockham FFT, radices 8,8,8,4. 256 threads.
// On entry: v[r] = x[t + 256 r] (natural order). On exit: result in
// buf[pidx(f)] natural order, all threads synced.
template <int SGN>
__device__ __forceinline__ void fft2048(float2* __restrict__ buf, float2* v, int t) {
  // stage0: m=1, p=t, q=0
  dft8<SGN>(v);
  tw8<SGN>(v, t);
  __syncthreads();               // callers' outstanding buf reads drain here
#pragma unroll
  for (int k = 0; k < 8; ++k) buf[pidx(8 * t + k)] = v[k];
  __syncthreads();
  // stage1: m=8
#pragma unroll
  for (int r = 0; r < 8; ++r) v[r] = buf[pidx(t + 256 * r)];
  dft8<SGN>(v);
  tw8<SGN>(v, t & ~7);
  __syncthreads();
  {
    int q = t & 7, p = t >> 3;
#pragma unroll
    for (int k = 0; k < 8; ++k) buf[pidx(q + 8 * (8 * p + k))] = v[k];
  }
  __syncthreads();
  // stage2: m=64
#pragma unroll
  for (int r = 0; r < 8; ++r) v[r] = buf[pidx(t + 256 * r)];
  dft8<SGN>(v);
  tw8<SGN>(v, t & ~63);
  __syncthreads();
  {
    int q = t & 63, p = t >> 6;
#pragma unroll
    for (int k = 0; k < 8; ++k) buf[pidx(q + 64 * (8 * p + k))] = v[k];
  }
  __syncthreads();
  // stage3: radix-4, m=512, p=0 -> twiddle-free; 2 butterflies/thread
  float2 w0[4], w1s[4];
#pragma unroll
  for (int r = 0; r < 4; ++r) {
    w0[r] = buf[pidx(t + 512 * r)];
    w1s[r] = buf[pidx(t + 256 + 512 * r)];
  }
  dft4<SGN>(w0);
  dft4<SGN>(w1s);
  __syncthreads();
#pragma unroll
  for (int k = 0; k < 4; ++k) {
    buf[pidx(t + 512 * k)] = w0[k];
    buf[pidx(t + 256 + 512 * k)] = w1s[k];
  }
  __syncthreads();
}

// ---------------------------------------------------------------------------
// Tiled transpose per batch, float4 on both global sides: in [R,C] -> out [C,R].
// 64x64 float tile; LDS [64][65] scalar accesses (both phases 2-way banked = free).
// grid (C/64, R/64, B), 256 threads.
// ---------------------------------------------------------------------------
__global__ __launch_bounds__(256) void transpose4_k(const float* __restrict__ in,
                                                    float* __restrict__ out,
                                                    int R, int C) {
  __shared__ float tile[64][65];
  const float* ip = in + (size_t)blockIdx.z * R * C;
  float* op = out + (size_t)blockIdx.z * R * C;
  int c0 = blockIdx.x * 64;
  int r0 = blockIdx.y * 64;
  int t = threadIdx.x;
  {
    int fx = t & 15;   // float4 index within 64-float row
    int rq = t >> 4;   // 0..15
#pragma unroll
    for (int i = 0; i < 4; ++i) {
      int r = rq + 16 * i;
      float4 v = *(const float4*)&ip[(size_t)(r0 + r) * C + (c0 + 4 * fx)];
      tile[r][4 * fx + 0] = v.x;
      tile[r][4 * fx + 1] = v.y;
      tile[r][4 * fx + 2] = v.z;
      tile[r][4 * fx + 3] = v.w;
    }
  }
  __syncthreads();
  {
    int gm = t & 15;   // r-group (float4 along r)
    int cq = t >> 4;   // 0..15
#pragma unroll
    for (int i = 0; i < 4; ++i) {
      int c = cq + 16 * i;
      float4 v;
      v.x = tile[4 * gm + 0][c];
      v.y = tile[4 * gm + 1][c];
      v.z = tile[4 * gm + 2][c];
      v.w = tile[4 * gm + 3][c];
      *(float4*)&op[(size_t)(c0 + c) * R + (r0 + 4 * gm)] = v;
    }
  }
}

// ---------------------------------------------------------------------------
// P1 (fallback, strided): per-(b,n) forward rfft, accumulate |X_f| into magsum.
// ---------------------------------------------------------------------------
template <int S>
__global__ __launch_bounds__(256) void p1_fft_mag(const float* __restrict__ src,
                                                  float* __restrict__ magsum) {
  __shared__ float2 buf[2304];
  int t = threadIdx.x;
  int blk = blockIdx.x;
  int b = blk >> 7;
  int n = blk & 127;
  const float* base = (S == 1) ? (src + (size_t)blk * L_)
                               : (src + (size_t)b * L_ * N_ + n);
  float2 v[8];
  if (S == 1) {
    const float2* r2 = (const float2*)base;
#pragma unroll
    for (int r = 0; r < 8; ++r) v[r] = r2[t + 256 * r];
  } else {
#pragma unroll
    for (int r = 0; r < 8; ++r) {
      int k = t + 256 * r;
      v[r] = make_float2(base[(size_t)(2 * k) * S], base[(size_t)(2 * k + 1) * S]);
    }
  }
  fft2048<-1>(buf, v, t);

  float* msum = magsum + (size_t)b * F_;
#pragma unroll
  for (int i = 0; i < 8; ++i) {
    int f = t + 256 * i;
    float mg;
    if (f == 0) {
      float2 z = buf[pidx(0)];
      mg = fabsf(z.x + z.y);
      atomicAdd(&msum[2048], fabsf(z.x - z.y));
    } else {
      float2 zf = buf[pidx(f)], zm = buf[pidx(2048 - f)];
      float Are = 0.5f * (zf.x + zm.x), Aim = 0.5f * (zf.y - zm.y);
      float Bre = 0.5f * (zf.y + zm.y), Bim = -0.5f * (zf.x - zm.x);
      float ang = (float)f * 0.00153398078788564117f;  // 2pi f / L
      float sv, cv;
      __sincosf(ang, &sv, &cv);
      float Xre = Are + cv * Bre + sv * Bim;
      float Xim = Aim + cv * Bim - sv * Bre;
      mg = sqrtf(Xre * Xre + Xim * Xim);
    }
    atomicAdd(&msum[f], mg);
  }
}

// ---------------------------------------------------------------------------
// P1 fast path: forward FFT, dump packed spectrum Z, accumulate |X_f|.
// Mirror-pair epilogue: each (f, 2048-f) pair shares one unpack+sincos.
// ---------------------------------------------------------------------------
__global__ __launch_bounds__(256) void p1_fft_mag_z(const float* __restrict__ src,
                                                    float2* __restrict__ zout,
                                                    float* __restrict__ magsum) {
  __shared__ float2 buf[2304];
  int t = threadIdx.x;
  int blk = blockIdx.x;
  int b = blk >> 7;
  const float2* r2 = (const float2*)(src + (size_t)blk * L_);
  float2 v[8];
#pragma unroll
  for (int r = 0; r < 8; ++r) v[r] = r2[t + 256 * r];
  fft2048<-1>(buf, v, t);

  float* msum = magsum + (size_t)b * F_;
  float2* zrow = zout + (size_t)blk * (size_t)M_;
#pragma unroll
  for (int i = 0; i < 4; ++i) {
    int f = t + 256 * i;
    if (f == 0) {
      float2 z = buf[pidx(0)];
      float2 zc = buf[pidx(1024)];
      zrow[0] = z;
      zrow[1024] = zc;
      atomicAdd(&msum[0], fabsf(z.x + z.y));
      atomicAdd(&msum[2048], fabsf(z.x - z.y));
      atomicAdd(&msum[1024], sqrtf(zc.x * zc.x + zc.y * zc.y));
    } else {
      float2 zf = buf[pidx(f)], zm = buf[pidx(2048 - f)];
      zrow[f] = zf;
      zrow[2048 - f] = zm;
      float Are = 0.5f * (zf.x + zm.x), Aim = 0.5f * (zf.y - zm.y);
      float Bre = 0.5f * (zf.y + zm.y), Bim = -0.5f * (zf.x - zm.x);
      float ang = (float)f * 0.00153398078788564117f;  // 2pi f / L
      float sv, cv;
      __sincosf(ang, &sv, &cv);
      float WBre = cv * Bre + sv * Bim;
      float WBim = cv * Bim - sv * Bre;
      float Xre = Are + WBre, Xim = Aim + WBim;
      float Xmre = Are - WBre, Xmim = Aim - WBim;  // |X_{2048-f}| (sign of Im irrelevant)
      atomicAdd(&msum[f], sqrtf(Xre * Xre + Xim * Xim));
      atomicAdd(&msum[2048 - f], sqrtf(Xmre * Xmre + Xmim * Xmim));
    }
  }
}

// ---------------------------------------------------------------------------
// magT[i*64 + b] = magsum[b*F + i] / 128   (tiny, L2-resident)
// ---------------------------------------------------------------------------
__global__ __launch_bounds__(256) void magt_k(const float* __restrict__ mag,
                                              float* __restrict__ magT) {
  int idx = blockIdx.x * 256 + threadIdx.x;
  if (idx >= 64 * F_) return;
  int f = idx >> 6, b = idx & 63;
  magT[idx] = mag[(size_t)b * F_ + f] * (1.0f / 128.0f);
}

// ---------------------------------------------------------------------------
// G1: hsum[b,o] += sum_i magT[i,b] * W1[i,o]   (split-K, atomics)
// 256 thr = one o per thread, all 64 b in registers; mag via uniform
// (scalar) loads -> inner loop is 1 coalesced W1 load + 64 FMA.
// grid (9, 63): 567 blocks * 4 waves ~ 9 waves/CU.
// ---------------------------------------------------------------------------
#define G1K 33
__global__ __launch_bounds__(256) void g1_gemm(const float* __restrict__ magT,
                                               const float* __restrict__ W1,
                                               float* __restrict__ hsum) {
  int o = blockIdx.x * 256 + threadIdx.x;
  if (o >= F_) return;
  int i0 = blockIdx.y * G1K;
  int i1 = min(F_, i0 + G1K);
  float acc[64];
#pragma unroll
  for (int b = 0; b < 64; ++b) acc[b] = 0.f;
  for (int i = i0; i < i1; ++i) {
    float w = W1[(size_t)i * F_ + o];
    const float* mrow = magT + (size_t)i * 64;  // wave-uniform -> scalar loads
#pragma unroll
    for (int b = 0; b < 64; ++b) acc[b] = fmaf(mrow[b], w, acc[b]);
  }
#pragma unroll
  for (int b = 0; b < 64; ++b) atomicAdd(&hsum[(size_t)b * F_ + o], acc[b]);
}

// ---------------------------------------------------------------------------
// G2: gate head + band-boundary mask -> wmask[b,f]
// ---------------------------------------------------------------------------
__global__ __launch_bounds__(256) void g2_gate(const float* __restrict__ hsum,
                                               const float* __restrict__ gb1,
                                               const float* __restrict__ W2,
                                               const float* __restrict__ gb2,
                                               const float* __restrict__ bbs,
                                               float* __restrict__ wmask) {
  __shared__ float red[256 * 8];
  __shared__ float wsm[8];
  __shared__ int idxs[9];
  int b = blockIdx.x;
  int t = threadIdx.x;
  float p[8];
#pragma unroll
  for (int e = 0; e < 8; ++e) p[e] = 0.f;
  for (int o = t; o < F_; o += 256) {
    float hv = hsum[(size_t)b * F_ + o] + gb1[o];
    hv = fmaxf(hv, 0.f);
    const float4* w2p = (const float4*)(W2 + (size_t)o * 8);
    float4 wa = w2p[0], wb = w2p[1];
    p[0] += hv * wa.x; p[1] += hv * wa.y; p[2] += hv * wa.z; p[3] += hv * wa.w;
    p[4] += hv * wb.x; p[5] += hv * wb.y; p[6] += hv * wb.z; p[7] += hv * wb.w;
  }
#pragma unroll
  for (int e = 0; e < 8; ++e) red[t * 8 + e] = p[e];
  __syncthreads();
  for (int s = 128; s >= 1; s >>= 1) {
    if (t < s) {
#pragma unroll
      for (int e = 0; e < 8; ++e) red[t * 8 + e] += red[(t + s) * 8 + e];
    }
    __syncthreads();
  }
  if (t == 0) {
    float lg[8];
    float mx = -1e30f;
#pragma unroll
    for (int e = 0; e < 8; ++e) { lg[e] = red[e] + gb2[e]; mx = fmaxf(mx, lg[e]); }
    float sm = 0.f;
#pragma unroll
    for (int e = 0; e < 8; ++e) { lg[e] = expf(lg[e] - mx); sm += lg[e]; }
    float inv = 1.f / sm;
#pragma unroll
    for (int e = 0; e < 8; ++e) wsm[e] = lg[e] * inv;
    float bv[7];
#pragma unroll
    for (int k = 0; k < 7; ++k) bv[k] = 1.f / (1.f + expf(-bbs[k]));
    for (int a = 1; a < 7; ++a) {
      float v = bv[a];
      int j = a - 1;
      while (j >= 0 && bv[j] > v) { bv[j + 1] = bv[j]; --j; }
      bv[j + 1] = v;
    }
    idxs[0] = 0;
    idxs[8] = F_;
    for (int k = 0; k < 7; ++k) {
      int v = (int)(bv[k] * (float)F_);
      v = min(max(v, 0), F_);
      idxs[k + 1] = v;
    }
  }
  __syncthreads();
  for (int f = t; f < F_; f += 256) {
    float wv = 0.f;
#pragma unroll
    for (int e = 0; e < 8; ++e)
      if (f >= idxs[e] && f < idxs[e + 1]) wv = wsm[e];
    wmask[(size_t)b * F_ + f] = wv;
  }
}

// ---------------------------------------------------------------------------
// P3 fast path: reads the packed spectrum Z written by p1_fft_mag_z (in/out,
// in-place per row). Stats come free from Z:
//   mean = (Z0.x+Z0.y)/4096 ; sum(x^2) = sum|Z_k|^2 / 2048  (Parseval).
// Then spectral filter + inverse FFT only.
// ---------------------------------------------------------------------------
__global__ __launch_bounds__(256) void p3_filter_z(float2* __restrict__ zbuf,
                                                   const float* __restrict__ wmask) {
  __shared__ float2 buf[2304];
  __shared__ float rb[8];
  __shared__ float sstat[2];
  int t = threadIdx.x;
  int blk = blockIdx.x;
  int b = blk >> 7;
  float2* zrow = zbuf + (size_t)blk * (size_t)M_;
  float2 v[8];
  float lsq = 0.f;
#pragma unroll
  for (int r = 0; r < 8; ++r) {
    float2 z = zrow[t + 256 * r];
    v[r] = z;
    lsq += z.x * z.x + z.y * z.y;
  }
#pragma unroll
  for (int r = 0; r < 8; ++r) buf[pidx(t + 256 * r)] = v[r];
  for (int off = 32; off > 0; off >>= 1) lsq += __shfl_down(lsq, off);
  {
    int lane = t & 63, wid = t >> 6;
    if (lane == 0) rb[wid] = lsq;
  }
  __syncthreads();
  if (t == 0) {
    float s2 = rb[0] + rb[1] + rb[2] + rb[3];        // sum |Z_k|^2
    float2 z0 = buf[pidx(0)];
    float mean = (z0.x + z0.y) * (1.0f / 4096.0f);
    float sumsq = s2 * (1.0f / 2048.0f);             // sum x^2 (Parseval)
    float var = sumsq * (1.0f / 4096.0f) - mean * mean + 1e-6f;
    sstat[0] = mean;
    sstat[1] = sqrtf(var);
  }
  __syncthreads();

  float mean = sstat[0], sdv = sstat[1];
  const float* wm = wmask + (size_t)b * F_;

  // spectral filter: thread handles f = t+256*i (i=0..3), paired with 2048-f
  float2 zf_[4], zm_[4];
#pragma unroll
  for (int i = 0; i < 4; ++i) {
    int f = t + 256 * i;
    int fm = (f == 0) ? 1024 : (2048 - f);
    zf_[i] = buf[pidx(f)];
    zm_[i] = buf[pidx(fm)];
  }
  __syncthreads();
#pragma unroll
  for (int i = 0; i < 4; ++i) {
    int f = t + 256 * i;
    if (f == 0) {
      float2 z0 = zf_[0];
      float2 zc = zm_[0];  // Z[1024]
      float X0 = (z0.x + z0.y) * (1.f + sdv * wm[0]);
      float XM = (z0.x - z0.y) * (1.f + sdv * wm[2048]);
      buf[pidx(0)] = make_float2(0.5f * (X0 + XM), 0.5f * (X0 - XM));
      float mc = 1.f + sdv * wm[1024];
      buf[pidx(1024)] = make_float2(zc.x * mc, zc.y * mc);
    } else {
      float2 zf = zf_[i], zm = zm_[i];
      float Are = 0.5f * (zf.x + zm.x), Aim = 0.5f * (zf.y - zm.y);
      float Bre = 0.5f * (zf.y + zm.y), Bim = -0.5f * (zf.x - zm.x);
      float ang = (float)f * 0.00153398078788564117f;  // 2pi f / L
      float sv, cv;
      __sincosf(ang, &sv, &cv);
      float WBre = cv * Bre + sv * Bim;
      float WBim = cv * Bim - sv * Bre;
      float Xre = Are + WBre, Xim = Aim + WBim;
      float Xmre = Are - WBre, Xmim = -(Aim - WBim);
      float mf = 1.f + sdv * wm[f];
      float mg = 1.f + sdv * wm[2048 - f];
      Xre *= mf; Xim *= mf;
      Xmre *= mg; Xmim *= mg;
      float Apre = 0.5f * (Xre + Xmre), Apim = 0.5f * (Xim - Xmim);
      float Tre = 0.5f * (Xre - Xmre), Tim = 0.5f * (Xim + Xmim);
      float Bpre = cv * Tre - sv * Tim;
      float Bpim = cv * Tim + sv * Tre;
      buf[pidx(f)] = make_float2(Apre - Bpim, Apim + Bpre);
      float Agre = 0.5f * (Xmre + Xre), Agim = 0.5f * (Xmim - Xim);
      float Tgre = 0.5f * (Xmre - Xre), Tgim = 0.5f * (Xmim + Xim);
      float Bgre = -(cv * Tgre + sv * Tgim);
      float Bgim = -(cv * Tgim - sv * Tgre);
      buf[pidx(2048 - f)] = make_float2(Agre - Bgim, Agim + Bgre);
    }
  }
  __syncthreads();
#pragma unroll
  for (int r = 0; r < 8; ++r) v[r] = buf[pidx(t + 256 * r)];
  fft2048<1>(buf, v, t);  // unnormalized inverse

  const float inv = 1.0f / 2048.0f;
#pragma unroll
  for (int r = 0; r < 8; ++r) {
    int k = t + 256 * r;
    float2 z = buf[pidx(k)];
    zrow[k] = make_float2(z.x * inv + mean, z.y * inv + mean);  // time domain
  }
}

// ---------------------------------------------------------------------------
// P3 fallback (strided): full fwd FFT + filter + inv FFT reading x directly.
// ---------------------------------------------------------------------------
template <int S>
__global__ __launch_bounds__(256) void p3_filter(const float* __restrict__ src,
                                                 const float* __restrict__ wmask,
                                                 float* __restrict__ dstp) {
  __shared__ float2 buf[2304];
  __shared__ float sstat[2];
  int t = threadIdx.x;
  int blk = blockIdx.x;
  int b = blk >> 7;
  int n = blk & 127;
  const float* base = (S == 1) ? (src + (size_t)blk * L_)
                               : (src + (size_t)b * L_ * N_ + n);
  float* obase = (S == 1) ? (dstp + (size_t)blk * L_)
                          : (dstp + (size_t)b * L_ * N_ + n);
  float2 v[8];
  float lsum = 0.f, lsq = 0.f;
  if (S == 1) {
    const float2* r2 = (const float2*)base;
#pragma unroll
    for (int r = 0; r < 8; ++r) {
      float2 z = r2[t + 256 * r];
      v[r] = z;
      lsum += z.x + z.y;
      lsq += z.x * z.x + z.y * z.y;
    }
  } else {
#pragma unroll
    for (int r = 0; r < 8; ++r) {
      int k = t + 256 * r;
      float2 z = make_float2(base[(size_t)(2 * k) * S], base[(size_t)(2 * k + 1) * S]);
      v[r] = z;
      lsum += z.x + z.y;
      lsq += z.x * z.x + z.y * z.y;
    }
  }
  for (int off = 32; off > 0; off >>= 1) {
    lsum += __shfl_down(lsum, off);
    lsq += __shfl_down(lsq, off);
  }
  {
    float* rb = (float*)buf;
    int lane = t & 63, wid = t >> 6;
    if (lane == 0) { rb[wid] = lsum; rb[8 + wid] = lsq; }
    __syncthreads();
    if (t == 0) {
      float s1 = rb[0] + rb[1] + rb[2] + rb[3];
      float s2 = rb[8] + rb[9] + rb[10] + rb[11];
      float mean = s1 * (1.0f / 4096.0f);
      float var = s2 * (1.0f / 4096.0f) - mean * mean + 1e-6f;
      sstat[0] = mean;
      sstat[1] = sqrtf(var);
    }
  }
  fft2048<-1>(buf, v, t);  // internal first sync protects rb reads

  float mean = sstat[0], sdv = sstat[1];
  const float* wm = wmask + (size_t)b * F_;

  float2 zf_[4], zm_[4];
#pragma unroll
  for (int i = 0; i < 4; ++i) {
    int f = t + 256 * i;
    int fm = (f == 0) ? 1024 : (2048 - f);
    zf_[i] = buf[pidx(f)];
    zm_[i] = buf[pidx(fm)];
  }
  __syncthreads();
#pragma unroll
  for (int i = 0; i < 4; ++i) {
    int f = t + 256 * i;
    if (f == 0) {
      float2 z0 = zf_[0];
      float2 zc = zm_[0];  // Z[1024]
      float X0 = (z0.x + z0.y) * (1.f + sdv * wm[0]);
      float XM = (z0.x - z0.y) * (1.f + sdv * wm[2048]);
      buf[pidx(0)] = make_float2(0.5f * (X0 + XM), 0.5f * (X0 - XM));
      float mc = 1.f + sdv * wm[1024];
      buf[pidx(1024)] = make_float2(zc.x * mc, zc.y * mc);
    } else {
      float2 zf = zf_[i], zm = zm_[i];
      float Are = 0.5f * (zf.x + zm.x), Aim = 0.5f * (zf.y - zm.y);
      float Bre = 0.5f * (zf.y + zm.y), Bim = -0.5f * (zf.x - zm.x);
      float ang = (float)f * 0.00153398078788564117f;  // 2pi f / L
      float sv, cv;
      __sincosf(ang, &sv, &cv);
      float WBre = cv * Bre + sv * Bim;
      float WBim = cv * Bim - sv * Bre;
      float Xre = Are + WBre, Xim = Aim + WBim;
      float Xmre = Are - WBre, Xmim = -(Aim - WBim);
      float mf = 1.f + sdv * wm[f];
      float mg = 1.f + sdv * wm[2048 - f];
      Xre *= mf; Xim *= mf;
      Xmre *= mg; Xmim *= mg;
      float Apre = 0.5f * (Xre + Xmre), Apim = 0.5f * (Xim - Xmim);
      float Tre = 0.5f * (Xre - Xmre), Tim = 0.5f * (Xim + Xmim);
      float Bpre = cv * Tre - sv * Tim;
      float Bpim = cv * Tim + sv * Tre;
      buf[pidx(f)] = make_float2(Apre - Bpim, Apim + Bpre);
      float Agre = 0.5f * (Xmre + Xre), Agim = 0.5f * (Xmim - Xim);
      float Tgre = 0.5f * (Xmre - Xre), Tgim = 0.5f * (Xmim + Xim);
      float Bgre = -(cv * Tgre + sv * Tgim);
      float Bgim = -(cv * Tgim - sv * Tgre);
      buf[pidx(2048 - f)] = make_float2(Agre - Bgim, Agim + Bgre);
    }
  }
  __syncthreads();
#pragma unroll
  for (int r = 0; r < 8; ++r) v[r] = buf[pidx(t + 256 * r)];
  fft2048<1>(buf, v, t);  // unnormalized inverse

  const float inv = 1.0f / 2048.0f;
  if (S == 1) {
    float2* o2 = (float2*)obase;
#pragma unroll
    for (int r = 0; r < 8; ++r) {
      int k = t + 256 * r;
      float2 z = buf[pidx(k)];
      o2[k] = make_float2(z.x * inv + mean, z.y * inv + mean);
    }
  } else {
#pragma unroll
    for (int r = 0; r < 8; ++r) {
      int k = t + 256 * r;
      float2 z = buf[pidx(k)];
      obase[(size_t)(2 * k) * S] = z.x * inv + mean;
      obase[(size_t)(2 * k + 1) * S] = z.y * inv + mean;
    }
  }
}

// ---------------------------------------------------------------------------
extern "C" void kernel_launch(void* const* d_in, const int* in_sizes, int n_in,
                              void* d_out, int out_size, void* d_ws,
                              size_t ws_size, hipStream_t stream) {
  const float* x = (const float*)d_in[0];
  const float* bbs = (const float*)d_in[1];
  const float* W1 = (const float*)d_in[2];
  const float* gb1 = (const float*)d_in[3];
  const float* W2 = (const float*)d_in[4];
  const float* gb2 = (const float*)d_in[5];
  float* out = (float*)d_out;

  const size_t bigElems = (size_t)B_ * N_ * L_;
  const size_t smallBytes = (size_t)3 * B_ * F_ * sizeof(float);
  const bool fast = ws_size >= bigElems * sizeof(float) + smallBytes;

  char* smallBase = (char*)d_ws + (fast ? bigElems * sizeof(float) : 0);
  float* magsum = (float*)smallBase;
  float* hsum = magsum + (size_t)B_ * F_;
  float* wmaskp = hsum + (size_t)B_ * F_;  // doubles as magT (B_==64)

  hipMemsetAsync(magsum, 0, (size_t)2 * B_ * F_ * sizeof(float), stream);

  const int g1x = (F_ + 255) / 256;            // 9
  const int g1y = (F_ + G1K - 1) / G1K;        // 63
  const int mtb = (64 * F_ + 255) / 256;       // 513
  if (fast) {
    float2* Z = (float2*)d_ws;
    transpose4_k<<<dim3(N_ / 64, L_ / 64, B_), 256, 0, stream>>>(x, out, L_, N_);
    p1_fft_mag_z<<<dim3(B_ * N_), 256, 0, stream>>>(out, Z, magsum);
    magt_k<<<dim3(mtb), 256, 0, stream>>>(magsum, wmaskp);
    g1_gemm<<<dim3(g1x, g1y), 256, 0, stream>>>(wmaskp, W1, hsum);
    g2_gate<<<dim3(B_), 256, 0, stream>>>(hsum, gb1, W2, gb2, bbs, wmaskp);
    p3_filter_z<<<dim3(B_ * N_), 256, 0, stream>>>(Z, wmaskp);
    transpose4_k<<<dim3(L_ / 64, N_ / 64, B_), 256, 0, stream>>>((float*)d_ws, out, N_, L_);
  } else {
    p1_fft_mag<N_><<<dim3(B_ * N_), 256, 0, stream>>>(x, magsum);
    magt_k<<<dim3(mtb), 256, 0, stream>>>(magsum, wmaskp);
    g1_gemm<<<dim3(g1x, g1y), 256, 0, stream>>>(wmaskp, W1, hsum);
    g2_gate<<<dim3(B_), 256, 0, stream>>>(hsum, gb1, W2, gb2, bbs, wmaskp);
    p3_filter<N_><<<dim3(B_ * N_), 256, 0, stream>>>(x, wmaskp, out);
  }
}

// Round 4
// 473.811 us; speedup vs baseline: 1.0505x; 1.0505x over previous
//
#include <hip/hip_runtime.h>

#define B_ 64
#define L_ 4096
#define N_ 128
#define F_ 2049
#define M_ 2048   // packed complex FFT size (L/2)

// padded LDS index: +1 float2 per 8 -> stage-0 scatter lands uniform mod 16
__device__ __forceinline__ int pidx(int a) { return a + (a >> 3); }

__device__ __forceinline__ float2 cadd(float2 a, float2 b) { return make_float2(a.x + b.x, a.y + b.y); }
__device__ __forceinline__ float2 csub(float2 a, float2 b) { return make_float2(a.x - b.x, a.y - b.y); }
__device__ __forceinline__ float2 cmul(float2 a, float2 b) {
  return make_float2(a.x * b.x - a.y * b.y, a.x * b.y + a.y * b.x);
}
template <int SGN>
__device__ __forceinline__ float2 mulsi(float2 a) {  // * (SGN * i)
  return (SGN > 0) ? make_float2(-a.y, a.x) : make_float2(a.y, -a.x);
}

template <int SGN>
__device__ __forceinline__ void dft8(float2* v) {
  const float C = 0.70710678118654752f;
  float2 t0 = cadd(v[0], v[4]), t1 = csub(v[0], v[4]);
  float2 t2 = cadd(v[2], v[6]), t3 = mulsi<SGN>(csub(v[2], v[6]));
  float2 t4 = cadd(v[1], v[5]), t5 = csub(v[1], v[5]);
  float2 t6 = cadd(v[3], v[7]), t7 = mulsi<SGN>(csub(v[3], v[7]));
  float2 u0 = cadd(t0, t2), u1 = csub(t0, t2);
  float2 u2 = cadd(t1, t3), u3 = csub(t1, t3);
  float2 u4 = cadd(t4, t6), u5 = csub(t4, t6);
  float2 u6 = cadd(t5, t7), u7 = csub(t5, t7);
  float2 w1 = make_float2(C, (SGN > 0) ? C : -C);    // e^{s i pi/4}
  float2 w3 = make_float2(-C, (SGN > 0) ? C : -C);   // e^{s i 3pi/4}
  float2 a5 = mulsi<SGN>(u5);
  float2 b6 = cmul(u6, w1);
  float2 b7 = cmul(u7, w3);
  v[0] = cadd(u0, u4); v[4] = csub(u0, u4);
  v[2] = cadd(u1, a5); v[6] = csub(u1, a5);
  v[1] = cadd(u2, b6); v[5] = csub(u2, b6);
  v[3] = cadd(u3, b7); v[7] = csub(u3, b7);
}

template <int SGN>
__device__ __forceinline__ void dft4(float2* v) {
  float2 e0 = cadd(v[0], v[2]), e1 = csub(v[0], v[2]);
  float2 o0 = cadd(v[1], v[3]), o1 = mulsi<SGN>(csub(v[1], v[3]));
  v[0] = cadd(e0, o0); v[2] = csub(e0, o0);
  v[1] = cadd(e1, o1); v[3] = csub(e1, o1);
}

// twiddle root for post-DFT Stockham twiddle
template <int SGN>
__device__ __forceinline__ float2 twroot(int pm) {
  float ang = (float)pm * 0.00306796157577128245f;  // 2pi/2048
  float sv, cv;
  __sincosf(ang, &sv, &cv);
  return make_float2(cv, (SGN > 0) ? sv : -sv);
}
__device__ __forceinline__ void tw8w(float2* v, float2 w) {
  float2 wk = w;
  v[1] = cmul(v[1], wk);
#pragma unroll
  for (int k = 2; k < 8; ++k) { wk = cmul(wk, w); v[k] = cmul(v[k], wk); }
}
template <int SGN>
__device__ __forceinline__ void tw8(float2* v, int pm) { tw8w(v, twroot<SGN>(pm)); }

// 2048-pt complex Stockham FFT, radices 8,8,8,4. 256 threads. (single row)
template <int SGN>
__device__ __forceinline__ void fft2048(float2* __restrict__ buf, float2* v, int t) {
  dft8<SGN>(v);
  tw8<SGN>(v, t);
  __syncthreads();
#pragma unroll
  for (int k = 0; k < 8; ++k) buf[pidx(8 * t + k)] = v[k];
  __syncthreads();
#pragma unroll
  for (int r = 0; r < 8; ++r) v[r] = buf[pidx(t + 256 * r)];
  dft8<SGN>(v);
  tw8<SGN>(v, t & ~7);
  __syncthreads();
  {
    int q = t & 7, p = t >> 3;
#pragma unroll
    for (int k = 0; k < 8; ++k) buf[pidx(q + 8 * (8 * p + k))] = v[k];
  }
  __syncthreads();
#pragma unroll
  for (int r = 0; r < 8; ++r) v[r] = buf[pidx(t + 256 * r)];
  dft8<SGN>(v);
  tw8<SGN>(v, t & ~63);
  __syncthreads();
  {
    int q = t & 63, p = t >> 6;
#pragma unroll
    for (int k = 0; k < 8; ++k) buf[pidx(q + 64 * (8 * p + k))] = v[k];
  }
  __syncthreads();
  float2 w0[4], w1s[4];
#pragma unroll
  for (int r = 0; r < 4; ++r) {
    w0[r] = buf[pidx(t + 512 * r)];
    w1s[r] = buf[pidx(t + 256 + 512 * r)];
  }
  dft4<SGN>(w0);
  dft4<SGN>(w1s);
  __syncthreads();
#pragma unroll
  for (int k = 0; k < 4; ++k) {
    buf[pidx(t + 512 * k)] = w0[k];
    buf[pidx(t + 256 + 512 * k)] = w1s[k];
  }
  __syncthreads();
}

// Two independent 2048-pt FFTs sharing the barrier schedule: 2x ILP between
// every pair of barriers; barrier overhead per row halved.
template <int SGN>
__device__ __forceinline__ void fft2048x2(float2* __restrict__ bufA, float2* __restrict__ bufB,
                                          float2* va, float2* vb, int t) {
  dft8<SGN>(va); dft8<SGN>(vb);
  { float2 w = twroot<SGN>(t); tw8w(va, w); tw8w(vb, w); }
  __syncthreads();
#pragma unroll
  for (int k = 0; k < 8; ++k) { bufA[pidx(8 * t + k)] = va[k]; bufB[pidx(8 * t + k)] = vb[k]; }
  __syncthreads();
#pragma unroll
  for (int r = 0; r < 8; ++r) { va[r] = bufA[pidx(t + 256 * r)]; vb[r] = bufB[pidx(t + 256 * r)]; }
  dft8<SGN>(va); dft8<SGN>(vb);
  { float2 w = twroot<SGN>(t & ~7); tw8w(va, w); tw8w(vb, w); }
  __syncthreads();
  {
    int q = t & 7, p = t >> 3;
#pragma unroll
    for (int k = 0; k < 8; ++k) {
      int a = pidx(q + 8 * (8 * p + k));
      bufA[a] = va[k]; bufB[a] = vb[k];
    }
  }
  __syncthreads();
#pragma unroll
  for (int r = 0; r < 8; ++r) { va[r] = bufA[pidx(t + 256 * r)]; vb[r] = bufB[pidx(t + 256 * r)]; }
  dft8<SGN>(va); dft8<SGN>(vb);
  { float2 w = twroot<SGN>(t & ~63); tw8w(va, w); tw8w(vb, w); }
  __syncthreads();
  {
    int q = t & 63, p = t >> 6;
#pragma unroll
    for (int k = 0; k < 8; ++k) {
      int a = pidx(q + 64 * (8 * p + k));
      bufA[a] = va[k]; bufB[a] = vb[k];
    }
  }
  __syncthreads();
  float2 wA0[4], wA1[4], wB0[4], wB1[4];
#pragma unroll
  for (int r = 0; r < 4; ++r) {
    wA0[r] = bufA[pidx(t + 512 * r)];
    wA1[r] = bufA[pidx(t + 256 + 512 * r)];
    wB0[r] = bufB[pidx(t + 512 * r)];
    wB1[r] = bufB[pidx(t + 256 + 512 * r)];
  }
  dft4<SGN>(wA0); dft4<SGN>(wA1); dft4<SGN>(wB0); dft4<SGN>(wB1);
  __syncthreads();
#pragma unroll
  for (int k = 0; k < 4; ++k) {
    bufA[pidx(t + 512 * k)] = wA0[k];
    bufA[pidx(t + 256 + 512 * k)] = wA1[k];
    bufB[pidx(t + 512 * k)] = wB0[k];
    bufB[pidx(t + 256 + 512 * k)] = wB1[k];
  }
  __syncthreads();
}

// ---------------------------------------------------------------------------
// Tiled transpose per batch, float4 on both global sides: in [R,C] -> out [C,R].
// ---------------------------------------------------------------------------
__global__ __launch_bounds__(256) void transpose4_k(const float* __restrict__ in,
                                                    float* __restrict__ out,
                                                    int R, int C) {
  __shared__ float tile[64][65];
  const float* ip = in + (size_t)blockIdx.z * R * C;
  float* op = out + (size_t)blockIdx.z * R * C;
  int c0 = blockIdx.x * 64;
  int r0 = blockIdx.y * 64;
  int t = threadIdx.x;
  {
    int fx = t & 15;
    int rq = t >> 4;
#pragma unroll
    for (int i = 0; i < 4; ++i) {
      int r = rq + 16 * i;
      float4 v = *(const float4*)&ip[(size_t)(r0 + r) * C + (c0 + 4 * fx)];
      tile[r][4 * fx + 0] = v.x;
      tile[r][4 * fx + 1] = v.y;
      tile[r][4 * fx + 2] = v.z;
      tile[r][4 * fx + 3] = v.w;
    }
  }
  __syncthreads();
  {
    int gm = t & 15;
    int cq = t >> 4;
#pragma unroll
    for (int i = 0; i < 4; ++i) {
      int c = cq + 16 * i;
      float4 v;
      v.x = tile[4 * gm + 0][c];
      v.y = tile[4 * gm + 1][c];
      v.z = tile[4 * gm + 2][c];
      v.w = tile[4 * gm + 3][c];
      *(float4*)&op[(size_t)(c0 + c) * R + (r0 + 4 * gm)] = v;
    }
  }
}

// ---------------------------------------------------------------------------
// P1 (fallback, strided): per-(b,n) forward rfft, accumulate |X_f| into magsum.
// ---------------------------------------------------------------------------
template <int S>
__global__ __launch_bounds__(256) void p1_fft_mag(const float* __restrict__ src,
                                                  float* __restrict__ magsum) {
  __shared__ float2 buf[2304];
  int t = threadIdx.x;
  int blk = blockIdx.x;
  int b = blk >> 7;
  int n = blk & 127;
  const float* base = (S == 1) ? (src + (size_t)blk * L_)
                               : (src + (size_t)b * L_ * N_ + n);
  float2 v[8];
  if (S == 1) {
    const float2* r2 = (const float2*)base;
#pragma unroll
    for (int r = 0; r < 8; ++r) v[r] = r2[t + 256 * r];
  } else {
#pragma unroll
    for (int r = 0; r < 8; ++r) {
      int k = t + 256 * r;
      v[r] = make_float2(base[(size_t)(2 * k) * S], base[(size_t)(2 * k + 1) * S]);
    }
  }
  fft2048<-1>(buf, v, t);

  float* msum = magsum + (size_t)b * F_;
#pragma unroll
  for (int i = 0; i < 8; ++i) {
    int f = t + 256 * i;
    float mg;
    if (f == 0) {
      float2 z = buf[pidx(0)];
      mg = fabsf(z.x + z.y);
      atomicAdd(&msum[2048], fabsf(z.x - z.y));
    } else {
      float2 zf = buf[pidx(f)], zm = buf[pidx(2048 - f)];
      float Are = 0.5f * (zf.x + zm.x), Aim = 0.5f * (zf.y - zm.y);
      float Bre = 0.5f * (zf.y + zm.y), Bim = -0.5f * (zf.x - zm.x);
      float ang = (float)f * 0.00153398078788564117f;  // 2pi f / L
      float sv, cv;
      __sincosf(ang, &sv, &cv);
      float Xre = Are + cv * Bre + sv * Bim;
      float Xim = Aim + cv * Bim - sv * Bre;
      mg = sqrtf(Xre * Xre + Xim * Xim);
    }
    atomicAdd(&msum[f], mg);
  }
}

// ---------------------------------------------------------------------------
// P1 fast path, 2 rows/block: forward FFTs, dump packed spectra, accumulate
// |X_f| (both rows summed before one atomic -> atomic count halved).
// ---------------------------------------------------------------------------
__global__ __launch_bounds__(256, 4) void p1_fft_mag_z2(const float* __restrict__ src,
                                                        float2* __restrict__ zout,
                                                        float* __restrict__ magsum) {
  __shared__ float2 bufA[2304];
  __shared__ float2 bufB[2304];
  int t = threadIdx.x;
  int blk = blockIdx.x;            // 0..B_*N_/2-1 ; rows 2*blk, 2*blk+1
  int b = blk >> 6;
  const float2* rA = (const float2*)(src + (size_t)(2 * blk) * L_);
  const float2* rB = rA + M_;
  float2 va[8], vb[8];
#pragma unroll
  for (int r = 0; r < 8; ++r) { va[r] = rA[t + 256 * r]; vb[r] = rB[t + 256 * r]; }
  fft2048x2<-1>(bufA, bufB, va, vb, t);

  float* msum = magsum + (size_t)b * F_;
  float2* zrA = zout + (size_t)(2 * blk) * (size_t)M_;
  float2* zrB = zrA + M_;
#pragma unroll
  for (int i = 0; i < 4; ++i) {
    int f = t + 256 * i;
    if (f == 0) {
      float2 zA = bufA[pidx(0)], zcA = bufA[pidx(1024)];
      float2 zB = bufB[pidx(0)], zcB = bufB[pidx(1024)];
      zrA[0] = zA; zrA[1024] = zcA;
      zrB[0] = zB; zrB[1024] = zcB;
      atomicAdd(&msum[0], fabsf(zA.x + zA.y) + fabsf(zB.x + zB.y));
      atomicAdd(&msum[2048], fabsf(zA.x - zA.y) + fabsf(zB.x - zB.y));
      atomicAdd(&msum[1024], sqrtf(zcA.x * zcA.x + zcA.y * zcA.y) +
                             sqrtf(zcB.x * zcB.x + zcB.y * zcB.y));
    } else {
      float2 zfA = bufA[pidx(f)], zmA = bufA[pidx(2048 - f)];
      float2 zfB = bufB[pidx(f)], zmB = bufB[pidx(2048 - f)];
      zrA[f] = zfA; zrA[2048 - f] = zmA;
      zrB[f] = zfB; zrB[2048 - f] = zmB;
      float ang = (float)f * 0.00153398078788564117f;  // 2pi f / L
      float sv, cv;
      __sincosf(ang, &sv, &cv);
      // row A
      float Are = 0.5f * (zfA.x + zmA.x), Aim = 0.5f * (zfA.y - zmA.y);
      float Bre = 0.5f * (zfA.y + zmA.y), Bim = -0.5f * (zfA.x - zmA.x);
      float WBre = cv * Bre + sv * Bim;
      float WBim = cv * Bim - sv * Bre;
      float XreA = Are + WBre, XimA = Aim + WBim;
      float XmreA = Are - WBre, XmimA = Aim - WBim;
      // row B
      float Cre = 0.5f * (zfB.x + zmB.x), Cim = 0.5f * (zfB.y - zmB.y);
      float Dre = 0.5f * (zfB.y + zmB.y), Dim = -0.5f * (zfB.x - zmB.x);
      float WDre = cv * Dre + sv * Dim;
      float WDim = cv * Dim - sv * Dre;
      float XreB = Cre + WDre, XimB = Cim + WDim;
      float XmreB = Cre - WDre, XmimB = Cim - WDim;
      atomicAdd(&msum[f], sqrtf(XreA * XreA + XimA * XimA) +
                          sqrtf(XreB * XreB + XimB * XimB));
      atomicAdd(&msum[2048 - f], sqrtf(XmreA * XmreA + XmimA * XmimA) +
                                 sqrtf(XmreB * XmreB + XmimB * XmimB));
    }
  }
}

// ---------------------------------------------------------------------------
// magT[i*64 + b] = magsum[b*F + i] / 128   (tiny, L2-resident)
// ---------------------------------------------------------------------------
__global__ __launch_bounds__(256) void magt_k(const float* __restrict__ mag,
                                              float* __restrict__ magT) {
  int idx = blockIdx.x * 256 + threadIdx.x;
  if (idx >= 64 * F_) return;
  int f = idx >> 6, b = idx & 63;
  magT[idx] = mag[(size_t)b * F_ + f] * (1.0f / 128.0f);
}

// ---------------------------------------------------------------------------
// G1: hsum[b,o] += sum_i magT[i,b] * W1[i,o]   (split-K, atomics)
// ---------------------------------------------------------------------------
#define G1K 33
__global__ __launch_bounds__(256) void g1_gemm(const float* __restrict__ magT,
                                               const float* __restrict__ W1,
                                               float* __restrict__ hsum) {
  int o = blockIdx.x * 256 + threadIdx.x;
  if (o >= F_) return;
  int i0 = blockIdx.y * G1K;
  int i1 = min(F_, i0 + G1K);
  float acc[64];
#pragma unroll
  for (int b = 0; b < 64; ++b) acc[b] = 0.f;
  for (int i = i0; i < i1; ++i) {
    float w = W1[(size_t)i * F_ + o];
    const float* mrow = magT + (size_t)i * 64;  // wave-uniform -> scalar loads
#pragma unroll
    for (int b = 0; b < 64; ++b) acc[b] = fmaf(mrow[b], w, acc[b]);
  }
#pragma unroll
  for (int b = 0; b < 64; ++b) atomicAdd(&hsum[(size_t)b * F_ + o], acc[b]);
}

// ---------------------------------------------------------------------------
// G2: gate head + band-boundary mask -> wmask[b,f]
// ---------------------------------------------------------------------------
__global__ __launch_bounds__(256) void g2_gate(const float* __restrict__ hsum,
                                               const float* __restrict__ gb1,
                                               const float* __restrict__ W2,
                                               const float* __restrict__ gb2,
                                               const float* __restrict__ bbs,
                                               float* __restrict__ wmask) {
  __shared__ float red[256 * 8];
  __shared__ float wsm[8];
  __shared__ int idxs[9];
  int b = blockIdx.x;
  int t = threadIdx.x;
  float p[8];
#pragma unroll
  for (int e = 0; e < 8; ++e) p[e] = 0.f;
  for (int o = t; o < F_; o += 256) {
    float hv = hsum[(size_t)b * F_ + o] + gb1[o];
    hv = fmaxf(hv, 0.f);
    const float4* w2p = (const float4*)(W2 + (size_t)o * 8);
    float4 wa = w2p[0], wb = w2p[1];
    p[0] += hv * wa.x; p[1] += hv * wa.y; p[2] += hv * wa.z; p[3] += hv * wa.w;
    p[4] += hv * wb.x; p[5] += hv * wb.y; p[6] += hv * wb.z; p[7] += hv * wb.w;
  }
#pragma unroll
  for (int e = 0; e < 8; ++e) red[t * 8 + e] = p[e];
  __syncthreads();
  for (int s = 128; s >= 1; s >>= 1) {
    if (t < s) {
#pragma unroll
      for (int e = 0; e < 8; ++e) red[t * 8 + e] += red[(t + s) * 8 + e];
    }
    __syncthreads();
  }
  if (t == 0) {
    float lg[8];
    float mx = -1e30f;
#pragma unroll
    for (int e = 0; e < 8; ++e) { lg[e] = red[e] + gb2[e]; mx = fmaxf(mx, lg[e]); }
    float sm = 0.f;
#pragma unroll
    for (int e = 0; e < 8; ++e) { lg[e] = expf(lg[e] - mx); sm += lg[e]; }
    float inv = 1.f / sm;
#pragma unroll
    for (int e = 0; e < 8; ++e) wsm[e] = lg[e] * inv;
    float bv[7];
#pragma unroll
    for (int k = 0; k < 7; ++k) bv[k] = 1.f / (1.f + expf(-bbs[k]));
    for (int a = 1; a < 7; ++a) {
      float v = bv[a];
      int j = a - 1;
      while (j >= 0 && bv[j] > v) { bv[j + 1] = bv[j]; --j; }
      bv[j + 1] = v;
    }
    idxs[0] = 0;
    idxs[8] = F_;
    for (int k = 0; k < 7; ++k) {
      int v = (int)(bv[k] * (float)F_);
      v = min(max(v, 0), F_);
      idxs[k + 1] = v;
    }
  }
  __syncthreads();
  for (int f = t; f < F_; f += 256) {
    float wv = 0.f;
#pragma unroll
    for (int e = 0; e < 8; ++e)
      if (f >= idxs[e] && f < idxs[e + 1]) wv = wsm[e];
    wmask[(size_t)b * F_ + f] = wv;
  }
}

// filter one conjugate pair (f !=0) in place via registers; returns new values
__device__ __forceinline__ void filter_pair(float2& zf, float2& zm, int f,
                                            float cv, float sv,
                                            float mf, float mg) {
  float Are = 0.5f * (zf.x + zm.x), Aim = 0.5f * (zf.y - zm.y);
  float Bre = 0.5f * (zf.y + zm.y), Bim = -0.5f * (zf.x - zm.x);
  float WBre = cv * Bre + sv * Bim;
  float WBim = cv * Bim - sv * Bre;
  float Xre = Are + WBre, Xim = Aim + WBim;
  float Xmre = Are - WBre, Xmim = -(Aim - WBim);
  Xre *= mf; Xim *= mf;
  Xmre *= mg; Xmim *= mg;
  float Apre = 0.5f * (Xre + Xmre), Apim = 0.5f * (Xim - Xmim);
  float Tre = 0.5f * (Xre - Xmre), Tim = 0.5f * (Xim + Xmim);
  float Bpre = cv * Tre - sv * Tim;
  float Bpim = cv * Tim + sv * Tre;
  zf = make_float2(Apre - Bpim, Apim + Bpre);
  float Agre = 0.5f * (Xmre + Xre), Agim = 0.5f * (Xmim - Xim);
  float Tgre = 0.5f * (Xmre - Xre), Tgim = 0.5f * (Xmim + Xim);
  float Bgre = -(cv * Tgre + sv * Tgim);
  float Bgim = -(cv * Tgim - sv * Tgre);
  zm = make_float2(Agre - Bgim, Agim + Bgre);
}

// ---------------------------------------------------------------------------
// P3 fast path, 2 rows/block: spectra in (from p1), filter, inverse FFT,
// time-domain rows out (in-place). Stats via Parseval.
// ---------------------------------------------------------------------------
__global__ __launch_bounds__(256, 4) void p3_filter_z2(float2* __restrict__ zbuf,
                                                       const float* __restrict__ wmask) {
  __shared__ float2 bufA[2304];
  __shared__ float2 bufB[2304];
  __shared__ float rb[16];
  __shared__ float sstat[4];
  int t = threadIdx.x;
  int blk = blockIdx.x;
  int b = blk >> 6;
  float2* zrA = zbuf + (size_t)(2 * blk) * (size_t)M_;
  float2* zrB = zrA + M_;
  float2 va[8], vb[8];
  float lsqA = 0.f, lsqB = 0.f;
#pragma unroll
  for (int r = 0; r < 8; ++r) {
    float2 zA = zrA[t + 256 * r];
    float2 zB = zrB[t + 256 * r];
    va[r] = zA; vb[r] = zB;
    lsqA += zA.x * zA.x + zA.y * zA.y;
    lsqB += zB.x * zB.x + zB.y * zB.y;
  }
#pragma unroll
  for (int r = 0; r < 8; ++r) {
    bufA[pidx(t + 256 * r)] = va[r];
    bufB[pidx(t + 256 * r)] = vb[r];
  }
  for (int off = 32; off > 0; off >>= 1) {
    lsqA += __shfl_down(lsqA, off);
    lsqB += __shfl_down(lsqB, off);
  }
  {
    int lane = t & 63, wid = t >> 6;
    if (lane == 0) { rb[wid] = lsqA; rb[8 + wid] = lsqB; }
  }
  __syncthreads();
  if (t < 2) {
    const float* rr = rb + 8 * t;
    float s2 = rr[0] + rr[1] + rr[2] + rr[3];
    float2 z0 = (t == 0) ? bufA[pidx(0)] : bufB[pidx(0)];
    float mean = (z0.x + z0.y) * (1.0f / 4096.0f);
    float sumsq = s2 * (1.0f / 2048.0f);
    float var = sumsq * (1.0f / 4096.0f) - mean * mean + 1e-6f;
    sstat[2 * t] = mean;
    sstat[2 * t + 1] = sqrtf(var);
  }
  __syncthreads();

  float meanA = sstat[0], sdvA = sstat[1];
  float meanB = sstat[2], sdvB = sstat[3];
  const float* wm = wmask + (size_t)b * F_;

  // filter: each (f, 2048-f) pair is owned by exactly one thread -> no
  // barrier between read and write-back.
#pragma unroll
  for (int i = 0; i < 4; ++i) {
    int f = t + 256 * i;
    if (f == 0) {
      float w0 = wm[0], wN = wm[2048], wC = wm[1024];
      {
        float2 z0 = bufA[pidx(0)], zc = bufA[pidx(1024)];
        float X0 = (z0.x + z0.y) * (1.f + sdvA * w0);
        float XM = (z0.x - z0.y) * (1.f + sdvA * wN);
        bufA[pidx(0)] = make_float2(0.5f * (X0 + XM), 0.5f * (X0 - XM));
        float mc = 1.f + sdvA * wC;
        bufA[pidx(1024)] = make_float2(zc.x * mc, zc.y * mc);
      }
      {
        float2 z0 = bufB[pidx(0)], zc = bufB[pidx(1024)];
        float X0 = (z0.x + z0.y) * (1.f + sdvB * w0);
        float XM = (z0.x - z0.y) * (1.f + sdvB * wN);
        bufB[pidx(0)] = make_float2(0.5f * (X0 + XM), 0.5f * (X0 - XM));
        float mc = 1.f + sdvB * wC;
        bufB[pidx(1024)] = make_float2(zc.x * mc, zc.y * mc);
      }
    } else {
      float ang = (float)f * 0.00153398078788564117f;  // 2pi f / L
      float sv, cv;
      __sincosf(ang, &sv, &cv);
      float wf = wm[f], wg = wm[2048 - f];
      {
        float2 zf = bufA[pidx(f)], zm = bufA[pidx(2048 - f)];
        filter_pair(zf, zm, f, cv, sv, 1.f + sdvA * wf, 1.f + sdvA * wg);
        bufA[pidx(f)] = zf; bufA[pidx(2048 - f)] = zm;
      }
      {
        float2 zf = bufB[pidx(f)], zm = bufB[pidx(2048 - f)];
        filter_pair(zf, zm, f, cv, sv, 1.f + sdvB * wf, 1.f + sdvB * wg);
        bufB[pidx(f)] = zf; bufB[pidx(2048 - f)] = zm;
      }
    }
  }
  __syncthreads();
#pragma unroll
  for (int r = 0; r < 8; ++r) {
    va[r] = bufA[pidx(t + 256 * r)];
    vb[r] = bufB[pidx(t + 256 * r)];
  }
  fft2048x2<1>(bufA, bufB, va, vb, t);  // unnormalized inverse

  const float inv = 1.0f / 2048.0f;
#pragma unroll
  for (int r = 0; r < 8; ++r) {
    int k = t + 256 * r;
    float2 zA = bufA[pidx(k)];
    float2 zB = bufB[pidx(k)];
    zrA[k] = make_float2(zA.x * inv + meanA, zA.y * inv + meanA);
    zrB[k] = make_float2(zB.x * inv + meanB, zB.y * inv + meanB);
  }
}

// ---------------------------------------------------------------------------
// P3 fallback (strided): full fwd FFT + filter + inv FFT reading x directly.
// ---------------------------------------------------------------------------
template <int S>
__global__ __launch_bounds__(256) void p3_filter(const float* __restrict__ src,
                                                 const float* __restrict__ wmask,
                                                 float* __restrict__ dstp) {
  __shared__ float2 buf[2304];
  __shared__ float sstat[2];
  int t = threadIdx.x;
  int blk = blockIdx.x;
  int b = blk >> 7;
  int n = blk & 127;
  const float* base = (S == 1) ? (src + (size_t)blk * L_)
                               : (src + (size_t)b * L_ * N_ + n);
  float* obase = (S == 1) ? (dstp + (size_t)blk * L_)
                          : (dstp + (size_t)b * L_ * N_ + n);
  float2 v[8];
  float lsum = 0.f, lsq = 0.f;
  if (S == 1) {
    const float2* r2 = (const float2*)base;
#pragma unroll
    for (int r = 0; r < 8; ++r) {
      float2 z = r2[t + 256 * r];
      v[r] = z;
      lsum += z.x + z.y;
      lsq += z.x * z.x + z.y * z.y;
    }
  } else {
#pragma unroll
    for (int r = 0; r < 8; ++r) {
      int k = t + 256 * r;
      float2 z = make_float2(base[(size_t)(2 * k) * S], base[(size_t)(2 * k + 1) * S]);
      v[r] = z;
      lsum += z.x + z.y;
      lsq += z.x * z.x + z.y * z.y;
    }
  }
  for (int off = 32; off > 0; off >>= 1) {
    lsum += __shfl_down(lsum, off);
    lsq += __shfl_down(lsq, off);
  }
  {
    float* rb = (float*)buf;
    int lane = t & 63, wid = t >> 6;
    if (lane == 0) { rb[wid] = lsum; rb[8 + wid] = lsq; }
    __syncthreads();
    if (t == 0) {
      float s1 = rb[0] + rb[1] + rb[2] + rb[3];
      float s2 = rb[8] + rb[9] + rb[10] + rb[11];
      float mean = s1 * (1.0f / 4096.0f);
      float var = s2 * (1.0f / 4096.0f) - mean * mean + 1e-6f;
      sstat[0] = mean;
      sstat[1] = sqrtf(var);
    }
  }
  fft2048<-1>(buf, v, t);  // internal first sync protects rb reads

  float mean = sstat[0], sdv = sstat[1];
  const float* wm = wmask + (size_t)b * F_;

#pragma unroll
  for (int i = 0; i < 4; ++i) {
    int f = t + 256 * i;
    if (f == 0) {
      float2 z0 = buf[pidx(0)];
      float2 zc = buf[pidx(1024)];
      float X0 = (z0.x + z0.y) * (1.f + sdv * wm[0]);
      float XM = (z0.x - z0.y) * (1.f + sdv * wm[2048]);
      buf[pidx(0)] = make_float2(0.5f * (X0 + XM), 0.5f * (X0 - XM));
      float mc = 1.f + sdv * wm[1024];
      buf[pidx(1024)] = make_float2(zc.x * mc, zc.y * mc);
    } else {
      float ang = (float)f * 0.00153398078788564117f;  // 2pi f / L
      float sv, cv;
      __sincosf(ang, &sv, &cv);
      float2 zf = buf[pidx(f)], zm = buf[pidx(2048 - f)];
      filter_pair(zf, zm, f, cv, sv, 1.f + sdv * wm[f], 1.f + sdv * wm[2048 - f]);
      buf[pidx(f)] = zf; buf[pidx(2048 - f)] = zm;
    }
  }
  __syncthreads();
#pragma unroll
  for (int r = 0; r < 8; ++r) v[r] = buf[pidx(t + 256 * r)];
  fft2048<1>(buf, v, t);  // unnormalized inverse

  const float inv = 1.0f / 2048.0f;
  if (S == 1) {
    float2* o2 = (float2*)obase;
#pragma unroll
    for (int r = 0; r < 8; ++r) {
      int k = t + 256 * r;
      float2 z = buf[pidx(k)];
      o2[k] = make_float2(z.x * inv + mean, z.y * inv + mean);
    }
  } else {
#pragma unroll
    for (int r = 0; r < 8; ++r) {
      int k = t + 256 * r;
      float2 z = buf[pidx(k)];
      obase[(size_t)(2 * k) * S] = z.x * inv + mean;
      obase[(size_t)(2 * k + 1) * S] = z.y * inv + mean;
    }
  }
}

// ---------------------------------------------------------------------------
extern "C" void kernel_launch(void* const* d_in, const int* in_sizes, int n_in,
                              void* d_out, int out_size, void* d_ws,
                              size_t ws_size, hipStream_t stream) {
  const float* x = (const float*)d_in[0];
  const float* bbs = (const float*)d_in[1];
  const float* W1 = (const float*)d_in[2];
  const float* gb1 = (const float*)d_in[3];
  const float* W2 = (const float*)d_in[4];
  const float* gb2 = (const float*)d_in[5];
  float* out = (float*)d_out;

  const size_t bigElems = (size_t)B_ * N_ * L_;
  const size_t smallBytes = (size_t)3 * B_ * F_ * sizeof(float);
  const bool fast = ws_size >= bigElems * sizeof(float) + smallBytes;

  char* smallBase = (char*)d_ws + (fast ? bigElems * sizeof(float) : 0);
  float* magsum = (float*)smallBase;
  float* hsum = magsum + (size_t)B_ * F_;
  float* wmaskp = hsum + (size_t)B_ * F_;  // doubles as magT (B_==64)

  hipMemsetAsync(magsum, 0, (size_t)2 * B_ * F_ * sizeof(float), stream);

  const int g1x = (F_ + 255) / 256;            // 9
  const int g1y = (F_ + G1K - 1) / G1K;        // 63
  const int mtb = (64 * F_ + 255) / 256;       // 513
  if (fast) {
    float2* Z = (float2*)d_ws;
    transpose4_k<<<dim3(N_ / 64, L_ / 64, B_), 256, 0, stream>>>(x, out, L_, N_);
    p1_fft_mag_z2<<<dim3(B_ * N_ / 2), 256, 0, stream>>>(out, Z, magsum);
    magt_k<<<dim3(mtb), 256, 0, stream>>>(magsum, wmaskp);
    g1_gemm<<<dim3(g1x, g1y), 256, 0, stream>>>(wmaskp, W1, hsum);
    g2_gate<<<dim3(B_), 256, 0, stream>>>(hsum, gb1, W2, gb2, bbs, wmaskp);
    p3_filter_z2<<<dim3(B_ * N_ / 2), 256, 0, stream>>>(Z, wmaskp);
    transpose4_k<<<dim3(L_ / 64, N_ / 64, B_), 256, 0, stream>>>((float*)d_ws, out, N_, L_);
  } else {
    p1_fft_mag<N_><<<dim3(B_ * N_), 256, 0, stream>>>(x, magsum);
    magt_k<<<dim3(mtb), 256, 0, stream>>>(magsum, wmaskp);
    g1_gemm<<<dim3(g1x, g1y), 256, 0, stream>>>(wmaskp, W1, hsum);
    g2_gate<<<dim3(B_), 256, 0, stream>>>(hsum, gb1, W2, gb2, bbs, wmaskp);
    p3_filter<N_><<<dim3(B_ * N_), 256, 0, stream>>>(x, wmaskp, out);
  }
}